// Round 2
// baseline (644.688 us; speedup 1.0000x reference)
//
#include <hip/hip_runtime.h>
#include <hip/hip_fp16.h>

#define BATCH 16
#define CH    64
#define TLEN  200
#define NP    30
#define HID   128
#define G4    512            // 4*HID
#define NSEQ  (BATCH * NP)   // 480

__device__ __forceinline__ float dot4(float4 a, float4 b) {
    return a.x * b.x + a.y * b.y + a.z * b.z + a.w * b.w;
}

__device__ __forceinline__ float sigm_fast(float x) {
    return __builtin_amdgcn_rcpf(1.0f + __expf(-x));
}

__device__ __forceinline__ float tanh_fast(float x) {
    float xc = fminf(15.0f, fmaxf(-15.0f, x));
    float e = __expf(2.0f * xc);
    return (e - 1.0f) * __builtin_amdgcn_rcpf(e + 1.0f);
}

// ---------------------------------------------------------------------------
// Phase 1: xg[n][t][g] = sum_c x[b][c][t][p] * W_ih[g][c] + b_ih[g] + b_hh[g]
// W_ih row held in 16 NAMED float4 registers (no indexable array -> no
// scratch demotion, which cost R1 ~300us of L2 re-streaming).
// ---------------------------------------------------------------------------
template <typename XT>
__global__ __launch_bounds__(512, 2) void xg_kernel(
    const float* __restrict__ x, const float* __restrict__ W_ih,
    const float* __restrict__ b_ih, const float* __restrict__ b_hh,
    XT* __restrict__ xg)
{
    const int t   = blockIdx.x;   // 0..199
    const int b   = blockIdx.y;   // 0..15
    const int tid = threadIdx.x;  // 0..511

    __shared__ float xs[NP][CH];

    {   // cooperative load of x[b, :, t, :]
        const int c = tid >> 3;
        const int l = tid & 7;
        const float* xr = x + ((size_t)(b * CH + c) * TLEN + t) * NP;
        for (int p = l; p < NP; p += 8) xs[p][c] = xr[p];
    }

    const int g = tid;
    const float4* wr = (const float4*)(W_ih + (size_t)g * CH);
#define LWI(i) const float4 w##i = wr[i];
    LWI(0) LWI(1) LWI(2) LWI(3) LWI(4) LWI(5) LWI(6) LWI(7)
    LWI(8) LWI(9) LWI(10) LWI(11) LWI(12) LWI(13) LWI(14) LWI(15)
#undef LWI
    const float bias = b_ih[g] + b_hh[g];
    __syncthreads();

    for (int p = 0; p < NP; ++p) {
        const float4* xv = (const float4*)(xs[p]);
        float a0 = 0.f, a1 = 0.f, a2 = 0.f, a3 = 0.f;
        a0 += dot4(w0,  xv[0]);  a1 += dot4(w1,  xv[1]);
        a2 += dot4(w2,  xv[2]);  a3 += dot4(w3,  xv[3]);
        a0 += dot4(w4,  xv[4]);  a1 += dot4(w5,  xv[5]);
        a2 += dot4(w6,  xv[6]);  a3 += dot4(w7,  xv[7]);
        a0 += dot4(w8,  xv[8]);  a1 += dot4(w9,  xv[9]);
        a2 += dot4(w10, xv[10]); a3 += dot4(w11, xv[11]);
        a0 += dot4(w12, xv[12]); a1 += dot4(w13, xv[13]);
        a2 += dot4(w14, xv[14]); a3 += dot4(w15, xv[15]);
        const float acc = bias + ((a0 + a1) + (a2 + a3));
        const int n = b * NP + p;
        xg[((size_t)n * TLEN + t) * G4 + g] = (XT)acc;
    }
}

// ---------------------------------------------------------------------------
// Phase 2: recurrent LSTM. One block = 2 sequences (240 blocks ~ 1/CU).
// W_hh row in 32 NAMED float4 registers (128 VGPRs). h broadcast from LDS.
// ---------------------------------------------------------------------------
template <typename XT>
__global__ __launch_bounds__(512, 2) void lstm_kernel(
    const XT* __restrict__ xg, const float* __restrict__ W_hh,
    const float* __restrict__ W_fc, const float* __restrict__ b_fc,
    float* __restrict__ out)
{
    const int pair = blockIdx.x;
    const int n0 = pair * 2;
    const int n1 = n0 + 1;
    const int tid = threadIdx.x;

    __shared__ float hs[2][HID];
    __shared__ float cs[2][HID];
    __shared__ float gl[2][G4];

    if (tid < 2 * HID) {
        hs[tid >> 7][tid & 127] = 0.0f;
        cs[tid >> 7][tid & 127] = 0.0f;
    }

    const float4* wr = (const float4*)(W_hh + (size_t)tid * HID);
#define LWH(i) const float4 w##i = wr[i];
    LWH(0)  LWH(1)  LWH(2)  LWH(3)  LWH(4)  LWH(5)  LWH(6)  LWH(7)
    LWH(8)  LWH(9)  LWH(10) LWH(11) LWH(12) LWH(13) LWH(14) LWH(15)
    LWH(16) LWH(17) LWH(18) LWH(19) LWH(20) LWH(21) LWH(22) LWH(23)
    LWH(24) LWH(25) LWH(26) LWH(27) LWH(28) LWH(29) LWH(30) LWH(31)
#undef LWH

    const XT* p0 = xg + (size_t)n0 * TLEN * G4 + tid;
    const XT* p1 = xg + (size_t)n1 * TLEN * G4 + tid;
    float xa = (float)p0[0];
    float xb = (float)p1[0];
    const float4* h0 = (const float4*)hs[0];
    const float4* h1 = (const float4*)hs[1];
    __syncthreads();

    for (int t = 0; t < TLEN; ++t) {
        float nxa = 0.f, nxb = 0.f;
        if (t + 1 < TLEN) {
            nxa = (float)p0[(size_t)(t + 1) * G4];
            nxb = (float)p1[(size_t)(t + 1) * G4];
        }

        float a0 = 0.f, a1 = 0.f, b0 = 0.f, b1 = 0.f;
#define DW(i, p) { float4 ha = h0[i]; float4 hb = h1[i]; \
                   a##p += dot4(w##i, ha); b##p += dot4(w##i, hb); }
        DW(0,0)  DW(1,1)  DW(2,0)  DW(3,1)  DW(4,0)  DW(5,1)  DW(6,0)  DW(7,1)
        DW(8,0)  DW(9,1)  DW(10,0) DW(11,1) DW(12,0) DW(13,1) DW(14,0) DW(15,1)
        DW(16,0) DW(17,1) DW(18,0) DW(19,1) DW(20,0) DW(21,1) DW(22,0) DW(23,1)
        DW(24,0) DW(25,1) DW(26,0) DW(27,1) DW(28,0) DW(29,1) DW(30,0) DW(31,1)
#undef DW
        gl[0][tid] = xa + (a0 + a1);
        gl[1][tid] = xb + (b0 + b1);
        __syncthreads();

        if (tid < 2 * HID) {
            const int s = tid >> 7, j = tid & 127;
            const float gi = gl[s][j];
            const float gf = gl[s][HID + j];
            const float gg = gl[s][2 * HID + j];
            const float go = gl[s][3 * HID + j];
            const float i = sigm_fast(gi);
            const float f = sigm_fast(gf);
            const float gt = tanh_fast(gg);
            const float o = sigm_fast(go);
            const float cn = f * cs[s][j] + i * gt;
            cs[s][j] = cn;
            hs[s][j] = o * tanh_fast(cn);
        }
        __syncthreads();
        xa = nxa;
        xb = nxb;
    }

    if (tid < 2 * CH) {
        const int s = tid >> 6, ch = tid & 63;
        const float4* wf = (const float4*)(W_fc + (size_t)ch * HID);
        const float4* hv = (const float4*)hs[s];
        float a0 = 0.f, a1 = 0.f;
#pragma unroll
        for (int j = 0; j < 32; j += 2) {
            a0 += dot4(wf[j], hv[j]);
            a1 += dot4(wf[j + 1], hv[j + 1]);
        }
        out[(size_t)(n0 + s) * CH + ch] = a0 + a1 + b_fc[ch];
    }
}

extern "C" void kernel_launch(void* const* d_in, const int* in_sizes, int n_in,
                              void* d_out, int out_size, void* d_ws, size_t ws_size,
                              hipStream_t stream) {
    (void)in_sizes; (void)n_in; (void)out_size;
    const float* x    = (const float*)d_in[0];
    const float* W_ih = (const float*)d_in[1];
    const float* W_hh = (const float*)d_in[2];
    const float* b_ih = (const float*)d_in[3];
    const float* b_hh = (const float*)d_in[4];
    const float* W_fc = (const float*)d_in[5];
    const float* b_fc = (const float*)d_in[6];
    float* out = (float*)d_out;

    const size_t need_f32 = (size_t)NSEQ * TLEN * G4 * sizeof(float);  // 196.6 MB
    if (ws_size >= need_f32) {
        float* xg = (float*)d_ws;
        xg_kernel<float><<<dim3(TLEN, BATCH), 512, 0, stream>>>(x, W_ih, b_ih, b_hh, xg);
        lstm_kernel<float><<<NSEQ / 2, 512, 0, stream>>>(xg, W_hh, W_fc, b_fc, out);
    } else {
        __half* xg = (__half*)d_ws;
        xg_kernel<__half><<<dim3(TLEN, BATCH), 512, 0, stream>>>(x, W_ih, b_ih, b_hh, xg);
        lstm_kernel<__half><<<NSEQ / 2, 512, 0, stream>>>(xg, W_hh, W_fc, b_fc, out);
    }
}